// Round 4
// baseline (901.354 us; speedup 1.0000x reference)
//
#include <hip/hip_runtime.h>

#define CDIM 128
#define NGRAPH 256
#define BSH 7                 // 128 nodes per fill-bucket
#define BCAP 4096             // LDS sort capacity (mean 2048, +45 sigma)

typedef unsigned short bf16_t;
typedef __attribute__((ext_vector_type(8))) short bf16x8;  // MFMA A/B frag (4 VGPRs)
typedef __attribute__((ext_vector_type(4))) float f32x4;   // MFMA C/D frag

__device__ __forceinline__ float bflo(unsigned u) { return __uint_as_float(u << 16); }
__device__ __forceinline__ float bfhi(unsigned u) { return __uint_as_float(u & 0xffff0000u); }
__device__ __forceinline__ unsigned short f2bf(float f) {
  unsigned u = __float_as_uint(f);
  u += 0x7fffu + ((u >> 16) & 1u);   // round-to-nearest-even
  return (unsigned short)(u >> 16);
}
__device__ __forceinline__ float bf2f(unsigned short s) {
  return __uint_as_float((unsigned)s << 16);
}

// ---------- CSR build ----------
__global__ void k_hist(const int* __restrict__ dst, int* __restrict__ counts, int E) {
  int e = blockIdx.x * blockDim.x + threadIdx.x;
  if (e < E) atomicAdd(&counts[dst[e]], 1);
}

__global__ __launch_bounds__(1024) void k_bsum(const int* __restrict__ counts,
    int* __restrict__ bsums, int N) {
  __shared__ int wsum[16];
  int tid = threadIdx.x;
  int base = blockIdx.x * 4096 + tid * 4;
  int4 c = make_int4(0, 0, 0, 0);
  if (base + 3 < N) c = *(const int4*)&counts[base];
  else {
    if (base + 0 < N) c.x = counts[base + 0];
    if (base + 1 < N) c.y = counts[base + 1];
    if (base + 2 < N) c.z = counts[base + 2];
  }
  int s = c.x + c.y + c.z + c.w;
#pragma unroll
  for (int ofs = 32; ofs > 0; ofs >>= 1) s += __shfl_down(s, ofs, 64);
  if ((tid & 63) == 0) wsum[tid >> 6] = s;
  __syncthreads();
  if (tid == 0) {
    int t = 0;
#pragma unroll
    for (int i = 0; i < 16; i++) t += wsum[i];
    bsums[blockIdx.x] = t;
  }
}

__global__ __launch_bounds__(1024) void k_boff(const int* __restrict__ bsums,
    int* __restrict__ boffs, int G) {
  __shared__ int sh[1024];
  int tid = threadIdx.x;
  int v = (tid < G) ? bsums[tid] : 0;
  sh[tid] = v;
  __syncthreads();
  for (int ofs = 1; ofs < 1024; ofs <<= 1) {
    int u = (tid >= ofs) ? sh[tid - ofs] : 0;
    __syncthreads();
    sh[tid] += u;
    __syncthreads();
  }
  if (tid < G) boffs[tid] = sh[tid] - v;
  if (tid == G) boffs[G] = (G > 0) ? sh[G - 1] : 0;
}

__global__ __launch_bounds__(1024) void k_scan2(const int* __restrict__ counts,
    const int* __restrict__ boffs, int* __restrict__ rowptr,
    float* __restrict__ dinv, int N) {
  __shared__ int wsum[16];
  int tid = threadIdx.x;
  int lane = tid & 63, wave = tid >> 6;
  int base = blockIdx.x * 4096 + tid * 4;
  int4 c = make_int4(0, 0, 0, 0);
  if (base + 3 < N) c = *(const int4*)&counts[base];
  else {
    if (base + 0 < N) c.x = counts[base + 0];
    if (base + 1 < N) c.y = counts[base + 1];
    if (base + 2 < N) c.z = counts[base + 2];
  }
  int tsum = c.x + c.y + c.z + c.w;
  int v = tsum;
#pragma unroll
  for (int ofs = 1; ofs < 64; ofs <<= 1) {
    int u = __shfl_up(v, ofs, 64);
    if (lane >= ofs) v += u;
  }
  if (lane == 63) wsum[wave] = v;
  __syncthreads();
  if (wave == 0) {
    int w = (lane < 16) ? wsum[lane] : 0;
#pragma unroll
    for (int ofs = 1; ofs < 16; ofs <<= 1) {
      int u = __shfl_up(w, ofs, 64);
      if (lane >= ofs) w += u;
    }
    if (lane < 16) wsum[lane] = w;
  }
  __syncthreads();
  int waveoff = (wave == 0) ? 0 : wsum[wave - 1];
  int excl = boffs[blockIdx.x] + waveoff + (v - tsum);
  int r[4]; r[0] = excl; r[1] = r[0] + c.x; r[2] = r[1] + c.y; r[3] = r[2] + c.z;
  int cc[4] = {c.x, c.y, c.z, c.w};
#pragma unroll
  for (int k = 0; k < 4; k++) {
    int idx = base + k;
    if (idx < N) {
      rowptr[idx] = r[k];
      dinv[idx] = rsqrtf((float)cc[k] + 1.0f);
    }
  }
  if (blockIdx.x == 0 && tid == 0) rowptr[N] = boffs[gridDim.x];
}

// bucket cursors: bcur[b] = rowptr[b*128]
__global__ __launch_bounds__(1024) void k_bcur(const int* __restrict__ rowptr,
    int* __restrict__ bcur, int NB) {
  int b = blockIdx.x * blockDim.x + threadIdx.x;
  if (b < NB) bcur[b] = rowptr[b << BSH];
}

// pass 1: append (src | dstlow<<20) to the dst's bucket region — sequential tails,
// no write amplification.
__global__ void k_bfill(const int* __restrict__ src, const int* __restrict__ dst,
                        int* __restrict__ bcur, unsigned* __restrict__ tmp, int E) {
  int e = blockIdx.x * blockDim.x + threadIdx.x;
  if (e < E) {
    int d = dst[e];
    int p = atomicAdd(&bcur[d >> BSH], 1);
    tmp[p] = (unsigned)src[e] | ((unsigned)(d & 127) << 20);
  }
}

// pass 2: per-bucket LDS counting sort -> coalesced col write.
__global__ __launch_bounds__(256) void k_csort(const unsigned* __restrict__ tmp,
    const int* __restrict__ rowptr, int* __restrict__ col, int N, int NB) {
  __shared__ int lcur[128];
  __shared__ unsigned buf[BCAP];
  int b = blockIdx.x;
  int n0 = b << BSH;
  int n1 = n0 + 128; if (n1 > N) n1 = N;
  int base = rowptr[n0];
  int cnt = rowptr[n1] - base;
  int tid = threadIdx.x;
  if (tid < 128) lcur[tid] = (n0 + tid < N) ? (rowptr[n0 + tid] - base) : 0;
  __syncthreads();
  if (cnt <= BCAP) {
    for (int i = tid; i < cnt; i += 256) {
      unsigned pk = tmp[base + i];
      int p = atomicAdd(&lcur[(pk >> 20) & 127], 1);
      buf[p] = pk & 0xFFFFFu;
    }
    __syncthreads();
    for (int i = tid; i < cnt; i += 256) col[base + i] = (int)buf[i];
  } else {  // overflow fallback (statistically never for uniform dst)
    for (int i = tid; i < cnt; i += 256) {
      unsigned pk = tmp[base + i];
      int p = atomicAdd(&lcur[(pk >> 20) & 127], 1);
      col[base + p] = (int)(pk & 0xFFFFFu);
    }
  }
}

// ---------- MFMA GEMM: [M x 128] @ [128 x 128], bf16 MFMA, fp32 acc, bf16 out ----
// BF16IN=0: A fp32; BF16IN=1: A bf16. W fp32 -> transposed bf16 LDS Wt[n][k].
#define WSTRIDE 136   // bf16 elems; 272 B rows -> bank rotation 4/row (2-way, free)
template <int BF16IN>
__global__ __launch_bounds__(256) void k_gemm(const void* __restrict__ Ap,
    const float* __restrict__ W, bf16_t* __restrict__ Co, int M) {
  __shared__ bf16_t Wt[128 * WSTRIDE];
  int tid = threadIdx.x;
  // stage W (128k x 128n fp32, row-major) -> Wt[n*WSTRIDE + k] bf16
  for (int i = tid; i < 4096; i += 256) {
    int k = i >> 5;
    int nq = (i & 31) << 2;
    float4 w = *(const float4*)&W[k * CDIM + nq];
    Wt[(nq + 0) * WSTRIDE + k] = f2bf(w.x);
    Wt[(nq + 1) * WSTRIDE + k] = f2bf(w.y);
    Wt[(nq + 2) * WSTRIDE + k] = f2bf(w.z);
    Wt[(nq + 3) * WSTRIDE + k] = f2bf(w.w);
  }
  __syncthreads();

  int wave = tid >> 6;
  int lane = tid & 63;
  int m = lane & 15;        // A row within 16-row tile
  int q = lane >> 4;        // quad: k-part for A/B, row-part for D
  int nstrips = (M + 63) >> 6;

  for (int s = blockIdx.x; s < nstrips; s += gridDim.x) {
    int rowA = s * 64 + wave * 16 + m;
    if (rowA > M - 1) rowA = M - 1;
    bf16x8 a[4];
#pragma unroll
    for (int c = 0; c < 4; c++) {
      if (BF16IN) {
        a[c] = *(const bf16x8*)((const bf16_t*)Ap + (size_t)rowA * CDIM + c * 32 + q * 8);
      } else {
        const float* ap = (const float*)Ap + (size_t)rowA * CDIM + c * 32 + q * 8;
        float4 f0 = *(const float4*)ap;
        float4 f1 = *(const float4*)(ap + 4);
        union { bf16x8 v; unsigned short u[8]; } ua;
        ua.u[0] = f2bf(f0.x); ua.u[1] = f2bf(f0.y); ua.u[2] = f2bf(f0.z); ua.u[3] = f2bf(f0.w);
        ua.u[4] = f2bf(f1.x); ua.u[5] = f2bf(f1.y); ua.u[6] = f2bf(f1.z); ua.u[7] = f2bf(f1.w);
        a[c] = ua.v;
      }
    }
#pragma unroll
    for (int t = 0; t < 8; t++) {
      f32x4 acc = {0.f, 0.f, 0.f, 0.f};
#pragma unroll
      for (int c = 0; c < 4; c++) {
        bf16x8 bv = *(const bf16x8*)&Wt[(t * 16 + m) * WSTRIDE + c * 32 + q * 8];
        acc = __builtin_amdgcn_mfma_f32_16x16x32_bf16(a[c], bv, acc, 0, 0, 0);
      }
#pragma unroll
      for (int r = 0; r < 4; r++) {
        int row = s * 64 + wave * 16 + q * 4 + r;
        if (row < M) Co[(size_t)row * CDIM + t * 16 + m] = f2bf(acc[r]);
      }
    }
  }
}

// ---------- per-node gather aggregation + bias + relu (one wave per node) ------
__global__ __launch_bounds__(256) void k_agg(const bf16_t* __restrict__ t,
    const int* __restrict__ rowptr, const int* __restrict__ col,
    const float* __restrict__ dinv, const float* __restrict__ bias,
    bf16_t* __restrict__ out, int N) {
  int wave = threadIdx.x >> 6;
  int lane = threadIdx.x & 63;
  int node = blockIdx.x * 4 + wave;
  if (node >= N) return;
  float di = dinv[node];
  unsigned su = ((const unsigned*)(t + (size_t)node * CDIM))[lane];
  float ax = bflo(su) * di;
  float ay = bfhi(su) * di;
  int beg = rowptr[node], end = rowptr[node + 1];
  for (int base = beg; base < end; base += 64) {
    int rem = end - base;
    int cnt = rem < 64 ? rem : 64;
    int sL = 0; float wL = 0.f;
    if (lane < cnt) { sL = col[base + lane]; wL = dinv[sL]; }
    int k = 0;
    for (; k + 3 < cnt; k += 4) {
      int s0 = __shfl(sL, k, 64),     s1 = __shfl(sL, k + 1, 64);
      int s2 = __shfl(sL, k + 2, 64), s3 = __shfl(sL, k + 3, 64);
      float w0 = __shfl(wL, k, 64),     w1 = __shfl(wL, k + 1, 64);
      float w2 = __shfl(wL, k + 2, 64), w3 = __shfl(wL, k + 3, 64);
      unsigned u0 = ((const unsigned*)(t + (size_t)s0 * CDIM))[lane];
      unsigned u1 = ((const unsigned*)(t + (size_t)s1 * CDIM))[lane];
      unsigned u2 = ((const unsigned*)(t + (size_t)s2 * CDIM))[lane];
      unsigned u3 = ((const unsigned*)(t + (size_t)s3 * CDIM))[lane];
      ax = fmaf(bflo(u0), w0, ax); ay = fmaf(bfhi(u0), w0, ay);
      ax = fmaf(bflo(u1), w1, ax); ay = fmaf(bfhi(u1), w1, ay);
      ax = fmaf(bflo(u2), w2, ax); ay = fmaf(bfhi(u2), w2, ay);
      ax = fmaf(bflo(u3), w3, ax); ay = fmaf(bfhi(u3), w3, ay);
    }
    for (; k < cnt; k++) {
      int s = __shfl(sL, k, 64);
      float w = __shfl(wL, k, 64);
      unsigned u = ((const unsigned*)(t + (size_t)s * CDIM))[lane];
      ax = fmaf(bflo(u), w, ax); ay = fmaf(bfhi(u), w, ay);
    }
  }
  float2 bb = ((const float2*)bias)[lane];
  float ox = fmaf(di, ax, bb.x);
  float oy = fmaf(di, ay, bb.y);
  ox = fmaxf(ox, 0.f); oy = fmaxf(oy, 0.f);
  unsigned o = ((unsigned)f2bf(oy) << 16) | f2bf(ox);
  ((unsigned*)(out + (size_t)node * CDIM))[lane] = o;
}

// ---------- global mean pool (batch is sorted), bf16 in, fp32 out ----------
__global__ __launch_bounds__(128) void k_pool(const bf16_t* __restrict__ h,
    const int* __restrict__ batch, float* __restrict__ g, int N) {
  int b = blockIdx.x;
  int lo = 0, hi = N;
  while (lo < hi) { int mid = (lo + hi) >> 1; if (batch[mid] < b) lo = mid + 1; else hi = mid; }
  int s = lo;
  lo = 0; hi = N;
  int key = b + 1;
  while (lo < hi) { int mid = (lo + hi) >> 1; if (batch[mid] < key) lo = mid + 1; else hi = mid; }
  int e = lo;
  int c = threadIdx.x;
  float acc = 0.f;
  for (int i = s; i < e; i++) acc += bf2f(h[(size_t)i * CDIM + c]);
  g[b * CDIM + c] = acc / fmaxf((float)(e - s), 1.f);
}

// ---------- MLP head ----------
__global__ __launch_bounds__(512) void k_mlp1(const float* __restrict__ g,
    const float* __restrict__ W, const float* __restrict__ b, float* __restrict__ o) {
  __shared__ float gs[CDIM];
  int bi = blockIdx.x, tid = threadIdx.x;
  if (tid < CDIM) gs[tid] = g[bi * CDIM + tid];
  __syncthreads();
  if (tid < 500) {
    float acc = b[tid];
#pragma unroll 4
    for (int k = 0; k < CDIM; k++) acc = fmaf(gs[k], W[k * 500 + tid], acc);
    o[bi * 500 + tid] = fmaxf(acc, 0.f);
  }
}

__global__ __launch_bounds__(128) void k_mlp2(const float* __restrict__ a,
    const float* __restrict__ W, const float* __restrict__ b, float* __restrict__ o) {
  __shared__ float as[500];
  int bi = blockIdx.x, tid = threadIdx.x;
  for (int k = tid; k < 500; k += 128) as[k] = a[bi * 500 + k];
  __syncthreads();
  if (tid < 100) {
    float acc = b[tid];
    for (int k = 0; k < 500; k++) acc = fmaf(as[k], W[k * 100 + tid], acc);
    o[bi * 100 + tid] = fmaxf(acc, 0.f);
  }
}

__global__ __launch_bounds__(64) void k_mlp3(const float* __restrict__ a,
    const float* __restrict__ w, const float* __restrict__ b, float* __restrict__ o) {
  int bi = blockIdx.x, lane = threadIdx.x;
  float v = a[bi * 100 + lane] * w[lane];
  if (lane + 64 < 100) v = fmaf(a[bi * 100 + lane + 64], w[lane + 64], v);
#pragma unroll
  for (int ofs = 32; ofs > 0; ofs >>= 1) v += __shfl_down(v, ofs, 64);
  if (lane == 0) o[bi] = v + b[0];
}

static inline size_t align_up(size_t v) { return (v + 255) & ~(size_t)255; }

extern "C" void kernel_launch(void* const* d_in, const int* in_sizes, int n_in,
                              void* d_out, int out_size, void* d_ws, size_t ws_size,
                              hipStream_t stream) {
  const float* x   = (const float*)d_in[0];
  const int*   ei  = (const int*)d_in[1];
  const int*   bat = (const int*)d_in[2];
  const float* W1  = (const float*)d_in[3];
  const float* b1  = (const float*)d_in[4];
  const float* W2  = (const float*)d_in[5];
  const float* b2  = (const float*)d_in[6];
  const float* Wm1 = (const float*)d_in[7];
  const float* bm1 = (const float*)d_in[8];
  const float* Wm2 = (const float*)d_in[9];
  const float* bm2 = (const float*)d_in[10];
  const float* Wm3 = (const float*)d_in[11];
  const float* bm3 = (const float*)d_in[12];
  float* out = (float*)d_out;

  const int E = in_sizes[1] / 2;
  const int N = in_sizes[2];
  const int* src = ei;
  const int* dst = ei + E;
  const int G  = (N + 4095) / 4096;
  const int NB = (N + 127) >> BSH;

  char* p = (char*)d_ws;
  bf16_t* t    = (bf16_t*)p;   p += align_up((size_t)N * CDIM * 2);
  bf16_t* h    = (bf16_t*)p;   p += align_up((size_t)N * CDIM * 2);
  int* counts  = (int*)p;      p += align_up((size_t)N * 4);
  int* rowptr  = (int*)p;      p += align_up((size_t)(N + 1) * 4);
  int* colx    = (int*)p;      p += align_up((size_t)E * 4);
  unsigned* tmp= (unsigned*)p; p += align_up((size_t)E * 4);
  float* dinv  = (float*)p;    p += align_up((size_t)N * 4);
  int* bsums   = (int*)p;      p += align_up((size_t)G * 4);
  int* boffs   = (int*)p;      p += align_up((size_t)(G + 1) * 4);
  int* bcur    = (int*)p;      p += align_up((size_t)NB * 4);
  float* gb    = (float*)p;    p += align_up((size_t)NGRAPH * CDIM * 4);
  float* m1    = (float*)p;    p += align_up((size_t)NGRAPH * 500 * 4);
  float* m2    = (float*)p;    p += align_up((size_t)NGRAPH * 100 * 4);
  (void)ws_size; (void)n_in; (void)out_size;

  hipMemsetAsync(counts, 0, (size_t)N * 4, stream);
  k_hist<<<(E + 255) / 256, 256, 0, stream>>>(dst, counts, E);
  k_bsum<<<G, 1024, 0, stream>>>(counts, bsums, N);
  k_boff<<<1, 1024, 0, stream>>>(bsums, boffs, G);
  k_scan2<<<G, 1024, 0, stream>>>(counts, boffs, rowptr, dinv, N);
  k_bcur<<<(NB + 1023) / 1024, 1024, 0, stream>>>(rowptr, bcur, NB);
  k_bfill<<<(E + 255) / 256, 256, 0, stream>>>(src, dst, bcur, tmp, E);
  k_csort<<<NB, 256, 0, stream>>>(tmp, rowptr, colx, N, NB);

  int nstrips = (N + 63) >> 6;
  int gblocks = nstrips < 1024 ? nstrips : 1024;
  k_gemm<0><<<gblocks, 256, 0, stream>>>(x, W1, t, N);
  k_agg<<<(N + 3) / 4, 256, 0, stream>>>(t, rowptr, colx, dinv, b1, h, N);
  k_gemm<1><<<gblocks, 256, 0, stream>>>(h, W2, t, N);
  k_agg<<<(N + 3) / 4, 256, 0, stream>>>(t, rowptr, colx, dinv, b2, h, N);

  k_pool<<<NGRAPH, 128, 0, stream>>>(h, bat, gb, N);
  k_mlp1<<<NGRAPH, 512, 0, stream>>>(gb, Wm1, bm1, m1);
  k_mlp2<<<NGRAPH, 128, 0, stream>>>(m1, Wm2, bm2, m2);
  k_mlp3<<<NGRAPH, 64, 0, stream>>>(m2, Wm3, bm3, out);
}

// Round 5
// 550.880 us; speedup vs baseline: 1.6362x; 1.6362x over previous
//
#include <hip/hip_runtime.h>

#define CDIM 128
#define NGRAPH 256
#define BSH 7                 // 128 nodes per bucket
#define BCAP 4096             // LDS sort capacity (mean 2048, +45 sigma)
#define NBLK 256              // blocks for two-pass scatter

typedef unsigned short bf16_t;
typedef __attribute__((ext_vector_type(8))) short bf16x8;  // MFMA A/B frag (4 VGPRs)
typedef __attribute__((ext_vector_type(4))) float f32x4;   // MFMA C/D frag

__device__ __forceinline__ float bflo(unsigned u) { return __uint_as_float(u << 16); }
__device__ __forceinline__ float bfhi(unsigned u) { return __uint_as_float(u & 0xffff0000u); }
__device__ __forceinline__ unsigned short f2bf(float f) {
  unsigned u = __float_as_uint(f);
  u += 0x7fffu + ((u >> 16) & 1u);   // round-to-nearest-even
  return (unsigned short)(u >> 16);
}
__device__ __forceinline__ float bf2f(unsigned short s) {
  return __uint_as_float((unsigned)s << 16);
}

// ---------- CSR build ----------
__global__ void k_hist(const int* __restrict__ dst, int* __restrict__ counts, int E) {
  int e = blockIdx.x * blockDim.x + threadIdx.x;
  if (e < E) atomicAdd(&counts[dst[e]], 1);
}

__global__ __launch_bounds__(1024) void k_bsum(const int* __restrict__ counts,
    int* __restrict__ bsums, int N) {
  __shared__ int wsum[16];
  int tid = threadIdx.x;
  int base = blockIdx.x * 4096 + tid * 4;
  int4 c = make_int4(0, 0, 0, 0);
  if (base + 3 < N) c = *(const int4*)&counts[base];
  else {
    if (base + 0 < N) c.x = counts[base + 0];
    if (base + 1 < N) c.y = counts[base + 1];
    if (base + 2 < N) c.z = counts[base + 2];
  }
  int s = c.x + c.y + c.z + c.w;
#pragma unroll
  for (int ofs = 32; ofs > 0; ofs >>= 1) s += __shfl_down(s, ofs, 64);
  if ((tid & 63) == 0) wsum[tid >> 6] = s;
  __syncthreads();
  if (tid == 0) {
    int t = 0;
#pragma unroll
    for (int i = 0; i < 16; i++) t += wsum[i];
    bsums[blockIdx.x] = t;
  }
}

__global__ __launch_bounds__(1024) void k_boff(const int* __restrict__ bsums,
    int* __restrict__ boffs, int G) {
  __shared__ int sh[1024];
  int tid = threadIdx.x;
  int v = (tid < G) ? bsums[tid] : 0;
  sh[tid] = v;
  __syncthreads();
  for (int ofs = 1; ofs < 1024; ofs <<= 1) {
    int u = (tid >= ofs) ? sh[tid - ofs] : 0;
    __syncthreads();
    sh[tid] += u;
    __syncthreads();
  }
  if (tid < G) boffs[tid] = sh[tid] - v;
  if (tid == G) boffs[G] = (G > 0) ? sh[G - 1] : 0;
}

// exclusive-scan tile kernel writing rowptr + dinv (counts -> CSR)
__global__ __launch_bounds__(1024) void k_scan2(const int* __restrict__ counts,
    const int* __restrict__ boffs, int* __restrict__ rowptr,
    float* __restrict__ dinv, int N) {
  __shared__ int wsum[16];
  int tid = threadIdx.x;
  int lane = tid & 63, wave = tid >> 6;
  int base = blockIdx.x * 4096 + tid * 4;
  int4 c = make_int4(0, 0, 0, 0);
  if (base + 3 < N) c = *(const int4*)&counts[base];
  else {
    if (base + 0 < N) c.x = counts[base + 0];
    if (base + 1 < N) c.y = counts[base + 1];
    if (base + 2 < N) c.z = counts[base + 2];
  }
  int tsum = c.x + c.y + c.z + c.w;
  int v = tsum;
#pragma unroll
  for (int ofs = 1; ofs < 64; ofs <<= 1) {
    int u = __shfl_up(v, ofs, 64);
    if (lane >= ofs) v += u;
  }
  if (lane == 63) wsum[wave] = v;
  __syncthreads();
  if (wave == 0) {
    int w = (lane < 16) ? wsum[lane] : 0;
#pragma unroll
    for (int ofs = 1; ofs < 16; ofs <<= 1) {
      int u = __shfl_up(w, ofs, 64);
      if (lane >= ofs) w += u;
    }
    if (lane < 16) wsum[lane] = w;
  }
  __syncthreads();
  int waveoff = (wave == 0) ? 0 : wsum[wave - 1];
  int excl = boffs[blockIdx.x] + waveoff + (v - tsum);
  int r[4]; r[0] = excl; r[1] = r[0] + c.x; r[2] = r[1] + c.y; r[3] = r[2] + c.z;
  int cc[4] = {c.x, c.y, c.z, c.w};
#pragma unroll
  for (int k = 0; k < 4; k++) {
    int idx = base + k;
    if (idx < N) {
      rowptr[idx] = r[k];
      dinv[idx] = rsqrtf((float)cc[k] + 1.0f);
    }
  }
  if (blockIdx.x == 0 && tid == 0) rowptr[N] = boffs[gridDim.x];
}

// generic exclusive-scan tile kernel (offsets only)
__global__ __launch_bounds__(1024) void k_scan3(const int* __restrict__ counts,
    const int* __restrict__ boffs, int* __restrict__ offs, int M) {
  __shared__ int wsum[16];
  int tid = threadIdx.x;
  int lane = tid & 63, wave = tid >> 6;
  int base = blockIdx.x * 4096 + tid * 4;
  int4 c = make_int4(0, 0, 0, 0);
  if (base + 3 < M) c = *(const int4*)&counts[base];
  else {
    if (base + 0 < M) c.x = counts[base + 0];
    if (base + 1 < M) c.y = counts[base + 1];
    if (base + 2 < M) c.z = counts[base + 2];
  }
  int tsum = c.x + c.y + c.z + c.w;
  int v = tsum;
#pragma unroll
  for (int ofs = 1; ofs < 64; ofs <<= 1) {
    int u = __shfl_up(v, ofs, 64);
    if (lane >= ofs) v += u;
  }
  if (lane == 63) wsum[wave] = v;
  __syncthreads();
  if (wave == 0) {
    int w = (lane < 16) ? wsum[lane] : 0;
#pragma unroll
    for (int ofs = 1; ofs < 16; ofs <<= 1) {
      int u = __shfl_up(w, ofs, 64);
      if (lane >= ofs) w += u;
    }
    if (lane < 16) wsum[lane] = w;
  }
  __syncthreads();
  int waveoff = (wave == 0) ? 0 : wsum[wave - 1];
  int excl = boffs[blockIdx.x] + waveoff + (v - tsum);
  int r[4]; r[0] = excl; r[1] = r[0] + c.x; r[2] = r[1] + c.y; r[3] = r[2] + c.z;
#pragma unroll
  for (int k = 0; k < 4; k++) {
    int idx = base + k;
    if (idx < M) offs[idx] = r[k];
  }
}

// pass A: per-block LDS histogram over buckets -> phist[bucket*NBLK + blk]
__global__ __launch_bounds__(1024) void k_phist(const int* __restrict__ dst,
    int* __restrict__ phist, int E, int NB) {
  __shared__ int hist[1024];
  int t = blockIdx.x, tid = threadIdx.x;
  for (int i = tid; i < NB; i += 1024) hist[i] = 0;
  __syncthreads();
  int tile = (E + NBLK - 1) / NBLK;
  int lo = t * tile;
  int hi = lo + tile; if (hi > E) hi = E;
  for (int i = lo + tid; i < hi; i += 1024) atomicAdd(&hist[dst[i] >> BSH], 1);
  __syncthreads();
  for (int i = tid; i < NB; i += 1024) phist[i * NBLK + t] = hist[i];
}

// pass B: exact-offset scatter, LDS cursors, zero global atomics.
__global__ __launch_bounds__(1024) void k_pscatter(const int* __restrict__ src,
    const int* __restrict__ dst, const int* __restrict__ poff,
    unsigned* __restrict__ tmp, int E, int NB) {
  __shared__ int cur[1024];
  int t = blockIdx.x, tid = threadIdx.x;
  for (int i = tid; i < NB; i += 1024) cur[i] = poff[i * NBLK + t];
  __syncthreads();
  int tile = (E + NBLK - 1) / NBLK;
  int lo = t * tile;
  int hi = lo + tile; if (hi > E) hi = E;
  for (int i = lo + tid; i < hi; i += 1024) {
    int d = dst[i];
    int p = atomicAdd(&cur[d >> BSH], 1);
    tmp[p] = (unsigned)src[i] | ((unsigned)(d & 127) << 20);
  }
}

// pass C: per-bucket LDS counting sort -> coalesced col write.
__global__ __launch_bounds__(256) void k_csort(const unsigned* __restrict__ tmp,
    const int* __restrict__ rowptr, int* __restrict__ col, int N, int NB) {
  __shared__ int lcur[128];
  __shared__ unsigned buf[BCAP];
  int b = blockIdx.x;
  int n0 = b << BSH;
  int n1 = n0 + 128; if (n1 > N) n1 = N;
  int base = rowptr[n0];
  int cnt = rowptr[n1] - base;
  int tid = threadIdx.x;
  if (tid < 128) lcur[tid] = (n0 + tid < N) ? (rowptr[n0 + tid] - base) : 0;
  __syncthreads();
  if (cnt <= BCAP) {
    for (int i = tid; i < cnt; i += 256) {
      unsigned pk = tmp[base + i];
      int p = atomicAdd(&lcur[(pk >> 20) & 127], 1);
      buf[p] = pk & 0xFFFFFu;
    }
    __syncthreads();
    for (int i = tid; i < cnt; i += 256) col[base + i] = (int)buf[i];
  } else {
    for (int i = tid; i < cnt; i += 256) {
      unsigned pk = tmp[base + i];
      int p = atomicAdd(&lcur[(pk >> 20) & 127], 1);
      col[base + p] = (int)(pk & 0xFFFFFu);
    }
  }
}

// ---------- MFMA GEMM: [M x 128] @ [128 x 128], bf16 MFMA, fp32 acc, bf16 out ----
#define WSTRIDE 136
template <int BF16IN>
__global__ __launch_bounds__(256) void k_gemm(const void* __restrict__ Ap,
    const float* __restrict__ W, bf16_t* __restrict__ Co, int M) {
  __shared__ bf16_t Wt[128 * WSTRIDE];
  int tid = threadIdx.x;
  for (int i = tid; i < 4096; i += 256) {
    int k = i >> 5;
    int nq = (i & 31) << 2;
    float4 w = *(const float4*)&W[k * CDIM + nq];
    Wt[(nq + 0) * WSTRIDE + k] = f2bf(w.x);
    Wt[(nq + 1) * WSTRIDE + k] = f2bf(w.y);
    Wt[(nq + 2) * WSTRIDE + k] = f2bf(w.z);
    Wt[(nq + 3) * WSTRIDE + k] = f2bf(w.w);
  }
  __syncthreads();

  int wave = tid >> 6;
  int lane = tid & 63;
  int m = lane & 15;
  int q = lane >> 4;
  int nstrips = (M + 63) >> 6;

  for (int s = blockIdx.x; s < nstrips; s += gridDim.x) {
    int rowA = s * 64 + wave * 16 + m;
    if (rowA > M - 1) rowA = M - 1;
    bf16x8 a[4];
#pragma unroll
    for (int c = 0; c < 4; c++) {
      if (BF16IN) {
        a[c] = *(const bf16x8*)((const bf16_t*)Ap + (size_t)rowA * CDIM + c * 32 + q * 8);
      } else {
        const float* ap = (const float*)Ap + (size_t)rowA * CDIM + c * 32 + q * 8;
        float4 f0 = *(const float4*)ap;
        float4 f1 = *(const float4*)(ap + 4);
        union { bf16x8 v; unsigned short u[8]; } ua;
        ua.u[0] = f2bf(f0.x); ua.u[1] = f2bf(f0.y); ua.u[2] = f2bf(f0.z); ua.u[3] = f2bf(f0.w);
        ua.u[4] = f2bf(f1.x); ua.u[5] = f2bf(f1.y); ua.u[6] = f2bf(f1.z); ua.u[7] = f2bf(f1.w);
        a[c] = ua.v;
      }
    }
#pragma unroll
    for (int t = 0; t < 8; t++) {
      f32x4 acc = {0.f, 0.f, 0.f, 0.f};
#pragma unroll
      for (int c = 0; c < 4; c++) {
        bf16x8 bv = *(const bf16x8*)&Wt[(t * 16 + m) * WSTRIDE + c * 32 + q * 8];
        acc = __builtin_amdgcn_mfma_f32_16x16x32_bf16(a[c], bv, acc, 0, 0, 0);
      }
#pragma unroll
      for (int r = 0; r < 4; r++) {
        int row = s * 64 + wave * 16 + q * 4 + r;
        if (row < M) Co[(size_t)row * CDIM + t * 16 + m] = f2bf(acc[r]);
      }
    }
  }
}

// ---------- per-node gather aggregation + bias + relu (one wave per node) ------
__global__ __launch_bounds__(256) void k_agg(const bf16_t* __restrict__ t,
    const int* __restrict__ rowptr, const int* __restrict__ col,
    const float* __restrict__ dinv, const float* __restrict__ bias,
    bf16_t* __restrict__ out, int N) {
  int wave = threadIdx.x >> 6;
  int lane = threadIdx.x & 63;
  int node = blockIdx.x * 4 + wave;
  if (node >= N) return;
  float di = dinv[node];
  unsigned su = ((const unsigned*)(t + (size_t)node * CDIM))[lane];
  float ax = bflo(su) * di;
  float ay = bfhi(su) * di;
  int beg = rowptr[node], end = rowptr[node + 1];
  for (int base = beg; base < end; base += 64) {
    int rem = end - base;
    int cnt = rem < 64 ? rem : 64;
    int sL = 0; float wL = 0.f;
    if (lane < cnt) { sL = col[base + lane]; wL = dinv[sL]; }
    int k = 0;
    for (; k + 3 < cnt; k += 4) {
      int s0 = __shfl(sL, k, 64),     s1 = __shfl(sL, k + 1, 64);
      int s2 = __shfl(sL, k + 2, 64), s3 = __shfl(sL, k + 3, 64);
      float w0 = __shfl(wL, k, 64),     w1 = __shfl(wL, k + 1, 64);
      float w2 = __shfl(wL, k + 2, 64), w3 = __shfl(wL, k + 3, 64);
      unsigned u0 = ((const unsigned*)(t + (size_t)s0 * CDIM))[lane];
      unsigned u1 = ((const unsigned*)(t + (size_t)s1 * CDIM))[lane];
      unsigned u2 = ((const unsigned*)(t + (size_t)s2 * CDIM))[lane];
      unsigned u3 = ((const unsigned*)(t + (size_t)s3 * CDIM))[lane];
      ax = fmaf(bflo(u0), w0, ax); ay = fmaf(bfhi(u0), w0, ay);
      ax = fmaf(bflo(u1), w1, ax); ay = fmaf(bfhi(u1), w1, ay);
      ax = fmaf(bflo(u2), w2, ax); ay = fmaf(bfhi(u2), w2, ay);
      ax = fmaf(bflo(u3), w3, ax); ay = fmaf(bfhi(u3), w3, ay);
    }
    for (; k < cnt; k++) {
      int s = __shfl(sL, k, 64);
      float w = __shfl(wL, k, 64);
      unsigned u = ((const unsigned*)(t + (size_t)s * CDIM))[lane];
      ax = fmaf(bflo(u), w, ax); ay = fmaf(bfhi(u), w, ay);
    }
  }
  float2 bb = ((const float2*)bias)[lane];
  float ox = fmaf(di, ax, bb.x);
  float oy = fmaf(di, ay, bb.y);
  ox = fmaxf(ox, 0.f); oy = fmaxf(oy, 0.f);
  unsigned o = ((unsigned)f2bf(oy) << 16) | f2bf(ox);
  ((unsigned*)(out + (size_t)node * CDIM))[lane] = o;
}

// ---------- global mean pool (batch is sorted), bf16 in, fp32 out ----------
__global__ __launch_bounds__(128) void k_pool(const bf16_t* __restrict__ h,
    const int* __restrict__ batch, float* __restrict__ g, int N) {
  int b = blockIdx.x;
  int lo = 0, hi = N;
  while (lo < hi) { int mid = (lo + hi) >> 1; if (batch[mid] < b) lo = mid + 1; else hi = mid; }
  int s = lo;
  lo = 0; hi = N;
  int key = b + 1;
  while (lo < hi) { int mid = (lo + hi) >> 1; if (batch[mid] < key) lo = mid + 1; else hi = mid; }
  int e = lo;
  int c = threadIdx.x;
  float acc = 0.f;
  for (int i = s; i < e; i++) acc += bf2f(h[(size_t)i * CDIM + c]);
  g[b * CDIM + c] = acc / fmaxf((float)(e - s), 1.f);
}

// ---------- MLP head ----------
__global__ __launch_bounds__(512) void k_mlp1(const float* __restrict__ g,
    const float* __restrict__ W, const float* __restrict__ b, float* __restrict__ o) {
  __shared__ float gs[CDIM];
  int bi = blockIdx.x, tid = threadIdx.x;
  if (tid < CDIM) gs[tid] = g[bi * CDIM + tid];
  __syncthreads();
  if (tid < 500) {
    float acc = b[tid];
#pragma unroll 4
    for (int k = 0; k < CDIM; k++) acc = fmaf(gs[k], W[k * 500 + tid], acc);
    o[bi * 500 + tid] = fmaxf(acc, 0.f);
  }
}

__global__ __launch_bounds__(128) void k_mlp2(const float* __restrict__ a,
    const float* __restrict__ W, const float* __restrict__ b, float* __restrict__ o) {
  __shared__ float as[500];
  int bi = blockIdx.x, tid = threadIdx.x;
  for (int k = tid; k < 500; k += 128) as[k] = a[bi * 500 + k];
  __syncthreads();
  if (tid < 100) {
    float acc = b[tid];
    for (int k = 0; k < 500; k++) acc = fmaf(as[k], W[k * 100 + tid], acc);
    o[bi * 100 + tid] = fmaxf(acc, 0.f);
  }
}

__global__ __launch_bounds__(64) void k_mlp3(const float* __restrict__ a,
    const float* __restrict__ w, const float* __restrict__ b, float* __restrict__ o) {
  int bi = blockIdx.x, lane = threadIdx.x;
  float v = a[bi * 100 + lane] * w[lane];
  if (lane + 64 < 100) v = fmaf(a[bi * 100 + lane + 64], w[lane + 64], v);
#pragma unroll
  for (int ofs = 32; ofs > 0; ofs >>= 1) v += __shfl_down(v, ofs, 64);
  if (lane == 0) o[bi] = v + b[0];
}

static inline size_t align_up(size_t v) { return (v + 255) & ~(size_t)255; }

extern "C" void kernel_launch(void* const* d_in, const int* in_sizes, int n_in,
                              void* d_out, int out_size, void* d_ws, size_t ws_size,
                              hipStream_t stream) {
  const float* x   = (const float*)d_in[0];
  const int*   ei  = (const int*)d_in[1];
  const int*   bat = (const int*)d_in[2];
  const float* W1  = (const float*)d_in[3];
  const float* b1  = (const float*)d_in[4];
  const float* W2  = (const float*)d_in[5];
  const float* b2  = (const float*)d_in[6];
  const float* Wm1 = (const float*)d_in[7];
  const float* bm1 = (const float*)d_in[8];
  const float* Wm2 = (const float*)d_in[9];
  const float* bm2 = (const float*)d_in[10];
  const float* Wm3 = (const float*)d_in[11];
  const float* bm3 = (const float*)d_in[12];
  float* out = (float*)d_out;

  const int E = in_sizes[1] / 2;
  const int N = in_sizes[2];
  const int* src = ei;
  const int* dst = ei + E;
  const int G  = (N + 4095) / 4096;
  const int NB = (N + 127) >> BSH;
  const int M  = NB * NBLK;              // phist elements
  const int G2 = (M + 4095) / 4096;

  char* p = (char*)d_ws;
  bf16_t* t    = (bf16_t*)p;   p += align_up((size_t)N * CDIM * 2);
  bf16_t* h    = (bf16_t*)p;   p += align_up((size_t)N * CDIM * 2);
  int* counts  = (int*)p;      p += align_up((size_t)N * 4);
  int* rowptr  = (int*)p;      p += align_up((size_t)(N + 1) * 4);
  int* colx    = (int*)p;      p += align_up((size_t)E * 4);
  unsigned* tmp= (unsigned*)p; p += align_up((size_t)E * 4);
  float* dinv  = (float*)p;    p += align_up((size_t)N * 4);
  int* bsumsA  = (int*)p;      p += align_up((size_t)G * 4);
  int* boffsA  = (int*)p;      p += align_up((size_t)(G + 1) * 4);
  int* phist   = (int*)p;      p += align_up((size_t)M * 4);
  int* poff    = (int*)p;      p += align_up((size_t)M * 4);
  int* bsumsB  = (int*)p;      p += align_up((size_t)G2 * 4);
  int* boffsB  = (int*)p;      p += align_up((size_t)(G2 + 1) * 4);
  float* gb    = (float*)p;    p += align_up((size_t)NGRAPH * CDIM * 4);
  float* m1    = (float*)p;    p += align_up((size_t)NGRAPH * 500 * 4);
  float* m2    = (float*)p;    p += align_up((size_t)NGRAPH * 100 * 4);
  (void)ws_size; (void)n_in; (void)out_size;

  hipMemsetAsync(counts, 0, (size_t)N * 4, stream);
  k_hist<<<(E + 255) / 256, 256, 0, stream>>>(dst, counts, E);
  k_bsum<<<G, 1024, 0, stream>>>(counts, bsumsA, N);
  k_boff<<<1, 1024, 0, stream>>>(bsumsA, boffsA, G);
  k_scan2<<<G, 1024, 0, stream>>>(counts, boffsA, rowptr, dinv, N);

  k_phist<<<NBLK, 1024, 0, stream>>>(dst, phist, E, NB);
  k_bsum<<<G2, 1024, 0, stream>>>(phist, bsumsB, M);
  k_boff<<<1, 1024, 0, stream>>>(bsumsB, boffsB, G2);
  k_scan3<<<G2, 1024, 0, stream>>>(phist, boffsB, poff, M);
  k_pscatter<<<NBLK, 1024, 0, stream>>>(src, dst, poff, tmp, E, NB);
  k_csort<<<NB, 256, 0, stream>>>(tmp, rowptr, colx, N, NB);

  int nstrips = (N + 63) >> 6;
  int gblocks = nstrips < 1024 ? nstrips : 1024;
  k_gemm<0><<<gblocks, 256, 0, stream>>>(x, W1, t, N);
  k_agg<<<(N + 3) / 4, 256, 0, stream>>>(t, rowptr, colx, dinv, b1, h, N);
  k_gemm<1><<<gblocks, 256, 0, stream>>>(h, W2, t, N);
  k_agg<<<(N + 3) / 4, 256, 0, stream>>>(t, rowptr, colx, dinv, b2, h, N);

  k_pool<<<NGRAPH, 128, 0, stream>>>(h, bat, gb, N);
  k_mlp1<<<NGRAPH, 512, 0, stream>>>(gb, Wm1, bm1, m1);
  k_mlp2<<<NGRAPH, 128, 0, stream>>>(m1, Wm2, bm2, m2);
  k_mlp3<<<NGRAPH, 64, 0, stream>>>(m2, Wm3, bm3, out);
}

// Round 6
// 496.968 us; speedup vs baseline: 1.8137x; 1.1085x over previous
//
#include <hip/hip_runtime.h>

#define CDIM 128
#define NGRAPH 256
#define BSH 7                 // 128 nodes per bucket
#define BCAP 4096             // LDS sort capacity (mean 2048, +45 sigma)
#define NBLK 256              // blocks for two-pass scatter
#define PCHUNK 512            // nodes per pooling block

typedef unsigned short bf16_t;
typedef __attribute__((ext_vector_type(8))) short bf16x8;  // MFMA A/B frag (4 VGPRs)
typedef __attribute__((ext_vector_type(4))) float f32x4;   // MFMA C/D frag

__device__ __forceinline__ float bflo(unsigned u) { return __uint_as_float(u << 16); }
__device__ __forceinline__ float bfhi(unsigned u) { return __uint_as_float(u & 0xffff0000u); }
__device__ __forceinline__ unsigned short f2bf(float f) {
  unsigned u = __float_as_uint(f);
  u += 0x7fffu + ((u >> 16) & 1u);   // round-to-nearest-even
  return (unsigned short)(u >> 16);
}
__device__ __forceinline__ float bf2f(unsigned short s) {
  return __uint_as_float((unsigned)s << 16);
}

// ---------- CSR build ----------
__global__ void k_hist(const int* __restrict__ dst, int* __restrict__ counts, int E) {
  int e = blockIdx.x * blockDim.x + threadIdx.x;
  if (e < E) atomicAdd(&counts[dst[e]], 1);
}

__global__ __launch_bounds__(1024) void k_bsum(const int* __restrict__ counts,
    int* __restrict__ bsums, int N) {
  __shared__ int wsum[16];
  int tid = threadIdx.x;
  int base = blockIdx.x * 4096 + tid * 4;
  int4 c = make_int4(0, 0, 0, 0);
  if (base + 3 < N) c = *(const int4*)&counts[base];
  else {
    if (base + 0 < N) c.x = counts[base + 0];
    if (base + 1 < N) c.y = counts[base + 1];
    if (base + 2 < N) c.z = counts[base + 2];
  }
  int s = c.x + c.y + c.z + c.w;
#pragma unroll
  for (int ofs = 32; ofs > 0; ofs >>= 1) s += __shfl_down(s, ofs, 64);
  if ((tid & 63) == 0) wsum[tid >> 6] = s;
  __syncthreads();
  if (tid == 0) {
    int t = 0;
#pragma unroll
    for (int i = 0; i < 16; i++) t += wsum[i];
    bsums[blockIdx.x] = t;
  }
}

__global__ __launch_bounds__(1024) void k_boff(const int* __restrict__ bsums,
    int* __restrict__ boffs, int G) {
  __shared__ int sh[1024];
  int tid = threadIdx.x;
  int v = (tid < G) ? bsums[tid] : 0;
  sh[tid] = v;
  __syncthreads();
  for (int ofs = 1; ofs < 1024; ofs <<= 1) {
    int u = (tid >= ofs) ? sh[tid - ofs] : 0;
    __syncthreads();
    sh[tid] += u;
    __syncthreads();
  }
  if (tid < G) boffs[tid] = sh[tid] - v;
  if (tid == G) boffs[G] = (G > 0) ? sh[G - 1] : 0;
}

// exclusive-scan tile kernel writing rowptr + dinv (counts -> CSR)
__global__ __launch_bounds__(1024) void k_scan2(const int* __restrict__ counts,
    const int* __restrict__ boffs, int* __restrict__ rowptr,
    float* __restrict__ dinv, int N) {
  __shared__ int wsum[16];
  int tid = threadIdx.x;
  int lane = tid & 63, wave = tid >> 6;
  int base = blockIdx.x * 4096 + tid * 4;
  int4 c = make_int4(0, 0, 0, 0);
  if (base + 3 < N) c = *(const int4*)&counts[base];
  else {
    if (base + 0 < N) c.x = counts[base + 0];
    if (base + 1 < N) c.y = counts[base + 1];
    if (base + 2 < N) c.z = counts[base + 2];
  }
  int tsum = c.x + c.y + c.z + c.w;
  int v = tsum;
#pragma unroll
  for (int ofs = 1; ofs < 64; ofs <<= 1) {
    int u = __shfl_up(v, ofs, 64);
    if (lane >= ofs) v += u;
  }
  if (lane == 63) wsum[wave] = v;
  __syncthreads();
  if (wave == 0) {
    int w = (lane < 16) ? wsum[lane] : 0;
#pragma unroll
    for (int ofs = 1; ofs < 16; ofs <<= 1) {
      int u = __shfl_up(w, ofs, 64);
      if (lane >= ofs) w += u;
    }
    if (lane < 16) wsum[lane] = w;
  }
  __syncthreads();
  int waveoff = (wave == 0) ? 0 : wsum[wave - 1];
  int excl = boffs[blockIdx.x] + waveoff + (v - tsum);
  int r[4]; r[0] = excl; r[1] = r[0] + c.x; r[2] = r[1] + c.y; r[3] = r[2] + c.z;
  int cc[4] = {c.x, c.y, c.z, c.w};
#pragma unroll
  for (int k = 0; k < 4; k++) {
    int idx = base + k;
    if (idx < N) {
      rowptr[idx] = r[k];
      dinv[idx] = rsqrtf((float)cc[k] + 1.0f);
    }
  }
  if (blockIdx.x == 0 && tid == 0) rowptr[N] = boffs[gridDim.x];
}

// generic exclusive-scan tile kernel (offsets only)
__global__ __launch_bounds__(1024) void k_scan3(const int* __restrict__ counts,
    const int* __restrict__ boffs, int* __restrict__ offs, int M) {
  __shared__ int wsum[16];
  int tid = threadIdx.x;
  int lane = tid & 63, wave = tid >> 6;
  int base = blockIdx.x * 4096 + tid * 4;
  int4 c = make_int4(0, 0, 0, 0);
  if (base + 3 < M) c = *(const int4*)&counts[base];
  else {
    if (base + 0 < M) c.x = counts[base + 0];
    if (base + 1 < M) c.y = counts[base + 1];
    if (base + 2 < M) c.z = counts[base + 2];
  }
  int tsum = c.x + c.y + c.z + c.w;
  int v = tsum;
#pragma unroll
  for (int ofs = 1; ofs < 64; ofs <<= 1) {
    int u = __shfl_up(v, ofs, 64);
    if (lane >= ofs) v += u;
  }
  if (lane == 63) wsum[wave] = v;
  __syncthreads();
  if (wave == 0) {
    int w = (lane < 16) ? wsum[lane] : 0;
#pragma unroll
    for (int ofs = 1; ofs < 16; ofs <<= 1) {
      int u = __shfl_up(w, ofs, 64);
      if (lane >= ofs) w += u;
    }
    if (lane < 16) wsum[lane] = w;
  }
  __syncthreads();
  int waveoff = (wave == 0) ? 0 : wsum[wave - 1];
  int excl = boffs[blockIdx.x] + waveoff + (v - tsum);
  int r[4]; r[0] = excl; r[1] = r[0] + c.x; r[2] = r[1] + c.y; r[3] = r[2] + c.z;
#pragma unroll
  for (int k = 0; k < 4; k++) {
    int idx = base + k;
    if (idx < M) offs[idx] = r[k];
  }
}

// pass A: per-block LDS histogram over buckets -> phist[bucket*NBLK + blk]
__global__ __launch_bounds__(1024) void k_phist(const int* __restrict__ dst,
    int* __restrict__ phist, int E, int NB) {
  __shared__ int hist[1024];
  int t = blockIdx.x, tid = threadIdx.x;
  for (int i = tid; i < NB; i += 1024) hist[i] = 0;
  __syncthreads();
  int tile = (E + NBLK - 1) / NBLK;
  int lo = t * tile;
  int hi = lo + tile; if (hi > E) hi = E;
  for (int i = lo + tid; i < hi; i += 1024) atomicAdd(&hist[dst[i] >> BSH], 1);
  __syncthreads();
  for (int i = tid; i < NB; i += 1024) phist[i * NBLK + t] = hist[i];
}

// pass B: exact-offset scatter, LDS cursors, zero global atomics.
__global__ __launch_bounds__(1024) void k_pscatter(const int* __restrict__ src,
    const int* __restrict__ dst, const int* __restrict__ poff,
    unsigned* __restrict__ tmp, int E, int NB) {
  __shared__ int cur[1024];
  int t = blockIdx.x, tid = threadIdx.x;
  for (int i = tid; i < NB; i += 1024) cur[i] = poff[i * NBLK + t];
  __syncthreads();
  int tile = (E + NBLK - 1) / NBLK;
  int lo = t * tile;
  int hi = lo + tile; if (hi > E) hi = E;
  for (int i = lo + tid; i < hi; i += 1024) {
    int d = dst[i];
    int p = atomicAdd(&cur[d >> BSH], 1);
    tmp[p] = (unsigned)src[i] | ((unsigned)(d & 127) << 20);
  }
}

// pass C: per-bucket LDS counting sort -> coalesced col write.
__global__ __launch_bounds__(256) void k_csort(const unsigned* __restrict__ tmp,
    const int* __restrict__ rowptr, int* __restrict__ col, int N, int NB) {
  __shared__ int lcur[128];
  __shared__ unsigned buf[BCAP];
  int b = blockIdx.x;
  int n0 = b << BSH;
  int n1 = n0 + 128; if (n1 > N) n1 = N;
  int base = rowptr[n0];
  int cnt = rowptr[n1] - base;
  int tid = threadIdx.x;
  if (tid < 128) lcur[tid] = (n0 + tid < N) ? (rowptr[n0 + tid] - base) : 0;
  __syncthreads();
  if (cnt <= BCAP) {
    for (int i = tid; i < cnt; i += 256) {
      unsigned pk = tmp[base + i];
      int p = atomicAdd(&lcur[(pk >> 20) & 127], 1);
      buf[p] = pk & 0xFFFFFu;
    }
    __syncthreads();
    for (int i = tid; i < cnt; i += 256) col[base + i] = (int)buf[i];
  } else {
    for (int i = tid; i < cnt; i += 256) {
      unsigned pk = tmp[base + i];
      int p = atomicAdd(&lcur[(pk >> 20) & 127], 1);
      col[base + p] = (int)(pk & 0xFFFFFu);
    }
  }
}

// ---------- MFMA GEMM: [M x 128] @ [128 x 128], bf16 MFMA, fp32 acc, bf16 out ----
#define WSTRIDE 136
template <int BF16IN>
__global__ __launch_bounds__(256) void k_gemm(const void* __restrict__ Ap,
    const float* __restrict__ W, bf16_t* __restrict__ Co, int M) {
  __shared__ bf16_t Wt[128 * WSTRIDE];
  int tid = threadIdx.x;
  for (int i = tid; i < 4096; i += 256) {
    int k = i >> 5;
    int nq = (i & 31) << 2;
    float4 w = *(const float4*)&W[k * CDIM + nq];
    Wt[(nq + 0) * WSTRIDE + k] = f2bf(w.x);
    Wt[(nq + 1) * WSTRIDE + k] = f2bf(w.y);
    Wt[(nq + 2) * WSTRIDE + k] = f2bf(w.z);
    Wt[(nq + 3) * WSTRIDE + k] = f2bf(w.w);
  }
  __syncthreads();

  int wave = tid >> 6;
  int lane = tid & 63;
  int m = lane & 15;
  int q = lane >> 4;
  int nstrips = (M + 63) >> 6;

  for (int s = blockIdx.x; s < nstrips; s += gridDim.x) {
    int rowA = s * 64 + wave * 16 + m;
    if (rowA > M - 1) rowA = M - 1;
    bf16x8 a[4];
#pragma unroll
    for (int c = 0; c < 4; c++) {
      if (BF16IN) {
        a[c] = *(const bf16x8*)((const bf16_t*)Ap + (size_t)rowA * CDIM + c * 32 + q * 8);
      } else {
        const float* ap = (const float*)Ap + (size_t)rowA * CDIM + c * 32 + q * 8;
        float4 f0 = *(const float4*)ap;
        float4 f1 = *(const float4*)(ap + 4);
        union { bf16x8 v; unsigned short u[8]; } ua;
        ua.u[0] = f2bf(f0.x); ua.u[1] = f2bf(f0.y); ua.u[2] = f2bf(f0.z); ua.u[3] = f2bf(f0.w);
        ua.u[4] = f2bf(f1.x); ua.u[5] = f2bf(f1.y); ua.u[6] = f2bf(f1.z); ua.u[7] = f2bf(f1.w);
        a[c] = ua.v;
      }
    }
#pragma unroll
    for (int t = 0; t < 8; t++) {
      f32x4 acc = {0.f, 0.f, 0.f, 0.f};
#pragma unroll
      for (int c = 0; c < 4; c++) {
        bf16x8 bv = *(const bf16x8*)&Wt[(t * 16 + m) * WSTRIDE + c * 32 + q * 8];
        acc = __builtin_amdgcn_mfma_f32_16x16x32_bf16(a[c], bv, acc, 0, 0, 0);
      }
#pragma unroll
      for (int r = 0; r < 4; r++) {
        int row = s * 64 + wave * 16 + q * 4 + r;
        if (row < M) Co[(size_t)row * CDIM + t * 16 + m] = f2bf(acc[r]);
      }
    }
  }
}

// ---------- per-node gather aggregation + bias + relu (one wave per node) ------
__global__ __launch_bounds__(256) void k_agg(const bf16_t* __restrict__ t,
    const int* __restrict__ rowptr, const int* __restrict__ col,
    const float* __restrict__ dinv, const float* __restrict__ bias,
    bf16_t* __restrict__ out, int N) {
  int wave = threadIdx.x >> 6;
  int lane = threadIdx.x & 63;
  int node = blockIdx.x * 4 + wave;
  if (node >= N) return;
  float di = dinv[node];
  unsigned su = ((const unsigned*)(t + (size_t)node * CDIM))[lane];
  float ax = bflo(su) * di;
  float ay = bfhi(su) * di;
  int beg = rowptr[node], end = rowptr[node + 1];
  for (int base = beg; base < end; base += 64) {
    int rem = end - base;
    int cnt = rem < 64 ? rem : 64;
    int sL = 0; float wL = 0.f;
    if (lane < cnt) { sL = col[base + lane]; wL = dinv[sL]; }
    int k = 0;
    for (; k + 3 < cnt; k += 4) {
      int s0 = __shfl(sL, k, 64),     s1 = __shfl(sL, k + 1, 64);
      int s2 = __shfl(sL, k + 2, 64), s3 = __shfl(sL, k + 3, 64);
      float w0 = __shfl(wL, k, 64),     w1 = __shfl(wL, k + 1, 64);
      float w2 = __shfl(wL, k + 2, 64), w3 = __shfl(wL, k + 3, 64);
      unsigned u0 = ((const unsigned*)(t + (size_t)s0 * CDIM))[lane];
      unsigned u1 = ((const unsigned*)(t + (size_t)s1 * CDIM))[lane];
      unsigned u2 = ((const unsigned*)(t + (size_t)s2 * CDIM))[lane];
      unsigned u3 = ((const unsigned*)(t + (size_t)s3 * CDIM))[lane];
      ax = fmaf(bflo(u0), w0, ax); ay = fmaf(bfhi(u0), w0, ay);
      ax = fmaf(bflo(u1), w1, ax); ay = fmaf(bfhi(u1), w1, ay);
      ax = fmaf(bflo(u2), w2, ax); ay = fmaf(bfhi(u2), w2, ay);
      ax = fmaf(bflo(u3), w3, ax); ay = fmaf(bfhi(u3), w3, ay);
    }
    for (; k < cnt; k++) {
      int s = __shfl(sL, k, 64);
      float w = __shfl(wL, k, 64);
      unsigned u = ((const unsigned*)(t + (size_t)s * CDIM))[lane];
      ax = fmaf(bflo(u), w, ax); ay = fmaf(bfhi(u), w, ay);
    }
  }
  float2 bb = ((const float2*)bias)[lane];
  float ox = fmaf(di, ax, bb.x);
  float oy = fmaf(di, ay, bb.y);
  ox = fmaxf(ox, 0.f); oy = fmaxf(oy, 0.f);
  unsigned o = ((unsigned)f2bf(oy) << 16) | f2bf(ox);
  ((unsigned*)(out + (size_t)node * CDIM))[lane] = o;
}

// ---------- global mean pool: node-parallel partial sums + atomics ----------
// batch is sorted; each wave covers nodes i0+wave, step 4, within a PCHUNK slice.
// Lanes hold 2 channels. Register accumulation, flush on graph change.
__global__ __launch_bounds__(256) void k_pool2(const bf16_t* __restrict__ h,
    const int* __restrict__ batch, float* __restrict__ gsum, int N) {
  int tid = threadIdx.x;
  int wave = tid >> 6, lane = tid & 63;
  int i0 = blockIdx.x * PCHUNK;
  int i1 = i0 + PCHUNK; if (i1 > N) i1 = N;
  float ax = 0.f, ay = 0.f;
  int curb = -1;
  for (int i = i0 + wave; i < i1; i += 4) {
    int b = batch[i];                 // wave-uniform broadcast load
    if (b != curb) {
      if (curb >= 0) {
        atomicAdd(&gsum[curb * CDIM + lane * 2], ax);
        atomicAdd(&gsum[curb * CDIM + lane * 2 + 1], ay);
      }
      curb = b; ax = 0.f; ay = 0.f;
    }
    unsigned u = ((const unsigned*)(h + (size_t)i * CDIM))[lane];
    ax += bflo(u); ay += bfhi(u);
  }
  if (curb >= 0) {
    atomicAdd(&gsum[curb * CDIM + lane * 2], ax);
    atomicAdd(&gsum[curb * CDIM + lane * 2 + 1], ay);
  }
}

// divide by per-graph node count (binary search over sorted batch), in place.
__global__ __launch_bounds__(128) void k_pooldiv(float* __restrict__ g,
    const int* __restrict__ batch, int N) {
  int b = blockIdx.x;
  int lo = 0, hi = N;
  while (lo < hi) { int mid = (lo + hi) >> 1; if (batch[mid] < b) lo = mid + 1; else hi = mid; }
  int s = lo;
  lo = 0; hi = N;
  int key = b + 1;
  while (lo < hi) { int mid = (lo + hi) >> 1; if (batch[mid] < key) lo = mid + 1; else hi = mid; }
  float inv = 1.f / fmaxf((float)(lo - s), 1.f);
  g[b * CDIM + threadIdx.x] *= inv;
}

// ---------- MLP head ----------
__global__ __launch_bounds__(512) void k_mlp1(const float* __restrict__ g,
    const float* __restrict__ W, const float* __restrict__ b, float* __restrict__ o) {
  __shared__ float gs[CDIM];
  int bi = blockIdx.x, tid = threadIdx.x;
  if (tid < CDIM) gs[tid] = g[bi * CDIM + tid];
  __syncthreads();
  if (tid < 500) {
    float acc = b[tid];
#pragma unroll 4
    for (int k = 0; k < CDIM; k++) acc = fmaf(gs[k], W[k * 500 + tid], acc);
    o[bi * 500 + tid] = fmaxf(acc, 0.f);
  }
}

__global__ __launch_bounds__(128) void k_mlp2(const float* __restrict__ a,
    const float* __restrict__ W, const float* __restrict__ b, float* __restrict__ o) {
  __shared__ float as[500];
  int bi = blockIdx.x, tid = threadIdx.x;
  for (int k = tid; k < 500; k += 128) as[k] = a[bi * 500 + k];
  __syncthreads();
  if (tid < 100) {
    float acc = b[tid];
    for (int k = 0; k < 500; k++) acc = fmaf(as[k], W[k * 100 + tid], acc);
    o[bi * 100 + tid] = fmaxf(acc, 0.f);
  }
}

__global__ __launch_bounds__(64) void k_mlp3(const float* __restrict__ a,
    const float* __restrict__ w, const float* __restrict__ b, float* __restrict__ o) {
  int bi = blockIdx.x, lane = threadIdx.x;
  float v = a[bi * 100 + lane] * w[lane];
  if (lane + 64 < 100) v = fmaf(a[bi * 100 + lane + 64], w[lane + 64], v);
#pragma unroll
  for (int ofs = 32; ofs > 0; ofs >>= 1) v += __shfl_down(v, ofs, 64);
  if (lane == 0) o[bi] = v + b[0];
}

static inline size_t align_up(size_t v) { return (v + 255) & ~(size_t)255; }

extern "C" void kernel_launch(void* const* d_in, const int* in_sizes, int n_in,
                              void* d_out, int out_size, void* d_ws, size_t ws_size,
                              hipStream_t stream) {
  const float* x   = (const float*)d_in[0];
  const int*   ei  = (const int*)d_in[1];
  const int*   bat = (const int*)d_in[2];
  const float* W1  = (const float*)d_in[3];
  const float* b1  = (const float*)d_in[4];
  const float* W2  = (const float*)d_in[5];
  const float* b2  = (const float*)d_in[6];
  const float* Wm1 = (const float*)d_in[7];
  const float* bm1 = (const float*)d_in[8];
  const float* Wm2 = (const float*)d_in[9];
  const float* bm2 = (const float*)d_in[10];
  const float* Wm3 = (const float*)d_in[11];
  const float* bm3 = (const float*)d_in[12];
  float* out = (float*)d_out;

  const int E = in_sizes[1] / 2;
  const int N = in_sizes[2];
  const int* src = ei;
  const int* dst = ei + E;
  const int G  = (N + 4095) / 4096;
  const int NB = (N + 127) >> BSH;
  const int M  = NB * NBLK;              // phist elements
  const int G2 = (M + 4095) / 4096;

  char* p = (char*)d_ws;
  bf16_t* t    = (bf16_t*)p;   p += align_up((size_t)N * CDIM * 2);
  bf16_t* h    = (bf16_t*)p;   p += align_up((size_t)N * CDIM * 2);
  int* counts  = (int*)p;      p += align_up((size_t)N * 4);
  int* rowptr  = (int*)p;      p += align_up((size_t)(N + 1) * 4);
  int* colx    = (int*)p;      p += align_up((size_t)E * 4);
  unsigned* tmp= (unsigned*)p; p += align_up((size_t)E * 4);
  float* dinv  = (float*)p;    p += align_up((size_t)N * 4);
  int* bsumsA  = (int*)p;      p += align_up((size_t)G * 4);
  int* boffsA  = (int*)p;      p += align_up((size_t)(G + 1) * 4);
  int* phist   = (int*)p;      p += align_up((size_t)M * 4);
  int* poff    = (int*)p;      p += align_up((size_t)M * 4);
  int* bsumsB  = (int*)p;      p += align_up((size_t)G2 * 4);
  int* boffsB  = (int*)p;      p += align_up((size_t)(G2 + 1) * 4);
  float* gb    = (float*)p;    p += align_up((size_t)NGRAPH * CDIM * 4);
  float* m1    = (float*)p;    p += align_up((size_t)NGRAPH * 500 * 4);
  float* m2    = (float*)p;    p += align_up((size_t)NGRAPH * 100 * 4);
  (void)ws_size; (void)n_in; (void)out_size;

  hipMemsetAsync(counts, 0, (size_t)N * 4, stream);
  hipMemsetAsync(gb, 0, (size_t)NGRAPH * CDIM * 4, stream);
  k_hist<<<(E + 255) / 256, 256, 0, stream>>>(dst, counts, E);
  k_bsum<<<G, 1024, 0, stream>>>(counts, bsumsA, N);
  k_boff<<<1, 1024, 0, stream>>>(bsumsA, boffsA, G);
  k_scan2<<<G, 1024, 0, stream>>>(counts, boffsA, rowptr, dinv, N);

  k_phist<<<NBLK, 1024, 0, stream>>>(dst, phist, E, NB);
  k_bsum<<<G2, 1024, 0, stream>>>(phist, bsumsB, M);
  k_boff<<<1, 1024, 0, stream>>>(bsumsB, boffsB, G2);
  k_scan3<<<G2, 1024, 0, stream>>>(phist, boffsB, poff, M);
  k_pscatter<<<NBLK, 1024, 0, stream>>>(src, dst, poff, tmp, E, NB);
  k_csort<<<NB, 256, 0, stream>>>(tmp, rowptr, colx, N, NB);

  int nstrips = (N + 63) >> 6;
  int gblocks = nstrips < 1024 ? nstrips : 1024;
  k_gemm<0><<<gblocks, 256, 0, stream>>>(x, W1, t, N);
  k_agg<<<(N + 3) / 4, 256, 0, stream>>>(t, rowptr, colx, dinv, b1, h, N);
  k_gemm<1><<<gblocks, 256, 0, stream>>>(h, W2, t, N);
  k_agg<<<(N + 3) / 4, 256, 0, stream>>>(t, rowptr, colx, dinv, b2, h, N);

  k_pool2<<<(N + PCHUNK - 1) / PCHUNK, 256, 0, stream>>>(h, bat, gb, N);
  k_pooldiv<<<NGRAPH, 128, 0, stream>>>(gb, bat, N);
  k_mlp1<<<NGRAPH, 512, 0, stream>>>(gb, Wm1, bm1, m1);
  k_mlp2<<<NGRAPH, 128, 0, stream>>>(m1, Wm2, bm2, m2);
  k_mlp3<<<NGRAPH, 64, 0, stream>>>(m2, Wm3, bm3, out);
}

// Round 7
// 420.869 us; speedup vs baseline: 2.1416x; 1.1808x over previous
//
#include <hip/hip_runtime.h>

#define CDIM 128
#define NGRAPH 256
#define BSH 7                 // 128 nodes per bucket
#define BCAP 4096             // LDS sort capacity (mean 2048, +45 sigma)
#define NBLK 256              // blocks for two-pass scatter
#define PCHUNK 512            // nodes per pooling block

typedef unsigned short bf16_t;
typedef __attribute__((ext_vector_type(8))) short bf16x8;  // MFMA A/B frag (4 VGPRs)
typedef __attribute__((ext_vector_type(4))) float f32x4;   // MFMA C/D frag

__device__ __forceinline__ float bflo(unsigned u) { return __uint_as_float(u << 16); }
__device__ __forceinline__ float bfhi(unsigned u) { return __uint_as_float(u & 0xffff0000u); }
__device__ __forceinline__ unsigned short f2bf(float f) {
  unsigned u = __float_as_uint(f);
  u += 0x7fffu + ((u >> 16) & 1u);   // round-to-nearest-even
  return (unsigned short)(u >> 16);
}
__device__ __forceinline__ float bf2f(unsigned short s) {
  return __uint_as_float((unsigned)s << 16);
}

// ---------- generic block-sum + scan kernels (for phist) ----------
__global__ __launch_bounds__(1024) void k_bsum(const int* __restrict__ counts,
    int* __restrict__ bsums, int N) {
  __shared__ int wsum[16];
  int tid = threadIdx.x;
  int base = blockIdx.x * 4096 + tid * 4;
  int4 c = make_int4(0, 0, 0, 0);
  if (base + 3 < N) c = *(const int4*)&counts[base];
  else {
    if (base + 0 < N) c.x = counts[base + 0];
    if (base + 1 < N) c.y = counts[base + 1];
    if (base + 2 < N) c.z = counts[base + 2];
  }
  int s = c.x + c.y + c.z + c.w;
#pragma unroll
  for (int ofs = 32; ofs > 0; ofs >>= 1) s += __shfl_down(s, ofs, 64);
  if ((tid & 63) == 0) wsum[tid >> 6] = s;
  __syncthreads();
  if (tid == 0) {
    int t = 0;
#pragma unroll
    for (int i = 0; i < 16; i++) t += wsum[i];
    bsums[blockIdx.x] = t;
  }
}

__global__ __launch_bounds__(1024) void k_boff(const int* __restrict__ bsums,
    int* __restrict__ boffs, int G) {
  __shared__ int sh[1024];
  int tid = threadIdx.x;
  int v = (tid < G) ? bsums[tid] : 0;
  sh[tid] = v;
  __syncthreads();
  for (int ofs = 1; ofs < 1024; ofs <<= 1) {
    int u = (tid >= ofs) ? sh[tid - ofs] : 0;
    __syncthreads();
    sh[tid] += u;
    __syncthreads();
  }
  if (tid < G) boffs[tid] = sh[tid] - v;
  if (tid == G) boffs[G] = (G > 0) ? sh[G - 1] : 0;
}

// generic exclusive-scan tile kernel (offsets only)
__global__ __launch_bounds__(1024) void k_scan3(const int* __restrict__ counts,
    const int* __restrict__ boffs, int* __restrict__ offs, int M) {
  __shared__ int wsum[16];
  int tid = threadIdx.x;
  int lane = tid & 63, wave = tid >> 6;
  int base = blockIdx.x * 4096 + tid * 4;
  int4 c = make_int4(0, 0, 0, 0);
  if (base + 3 < M) c = *(const int4*)&counts[base];
  else {
    if (base + 0 < M) c.x = counts[base + 0];
    if (base + 1 < M) c.y = counts[base + 1];
    if (base + 2 < M) c.z = counts[base + 2];
  }
  int tsum = c.x + c.y + c.z + c.w;
  int v = tsum;
#pragma unroll
  for (int ofs = 1; ofs < 64; ofs <<= 1) {
    int u = __shfl_up(v, ofs, 64);
    if (lane >= ofs) v += u;
  }
  if (lane == 63) wsum[wave] = v;
  __syncthreads();
  if (wave == 0) {
    int w = (lane < 16) ? wsum[lane] : 0;
#pragma unroll
    for (int ofs = 1; ofs < 16; ofs <<= 1) {
      int u = __shfl_up(w, ofs, 64);
      if (lane >= ofs) w += u;
    }
    if (lane < 16) wsum[lane] = w;
  }
  __syncthreads();
  int waveoff = (wave == 0) ? 0 : wsum[wave - 1];
  int excl = boffs[blockIdx.x] + waveoff + (v - tsum);
  int r[4]; r[0] = excl; r[1] = r[0] + c.x; r[2] = r[1] + c.y; r[3] = r[2] + c.z;
#pragma unroll
  for (int k = 0; k < 4; k++) {
    int idx = base + k;
    if (idx < M) offs[idx] = r[k];
  }
}

// pass A: per-block LDS histogram over buckets -> phist[bucket*NBLK + blk]
__global__ __launch_bounds__(1024) void k_phist(const int* __restrict__ dst,
    int* __restrict__ phist, int E, int NB) {
  __shared__ int hist[1024];
  int t = blockIdx.x, tid = threadIdx.x;
  for (int i = tid; i < NB; i += 1024) hist[i] = 0;
  __syncthreads();
  int tile = (E + NBLK - 1) / NBLK;
  int lo = t * tile;
  int hi = lo + tile; if (hi > E) hi = E;
  for (int i = lo + tid; i < hi; i += 1024) atomicAdd(&hist[dst[i] >> BSH], 1);
  __syncthreads();
  for (int i = tid; i < NB; i += 1024) phist[i * NBLK + t] = hist[i];
}

// pass B: exact-offset scatter, LDS cursors, zero global atomics.
__global__ __launch_bounds__(1024) void k_pscatter(const int* __restrict__ src,
    const int* __restrict__ dst, const int* __restrict__ poff,
    unsigned* __restrict__ tmp, int E, int NB) {
  __shared__ int cur[1024];
  int t = blockIdx.x, tid = threadIdx.x;
  for (int i = tid; i < NB; i += 1024) cur[i] = poff[i * NBLK + t];
  __syncthreads();
  int tile = (E + NBLK - 1) / NBLK;
  int lo = t * tile;
  int hi = lo + tile; if (hi > E) hi = E;
  for (int i = lo + tid; i < hi; i += 1024) {
    int d = dst[i];
    int p = atomicAdd(&cur[d >> BSH], 1);
    tmp[p] = (unsigned)src[i] | ((unsigned)(d & 127) << 20);
  }
}

// pass C: per-bucket LDS histogram + scan + counting sort.
// Produces rowptr, dinv, and sorted col — replaces the global k_hist/scan chain.
__global__ __launch_bounds__(256) void k_csort2(const unsigned* __restrict__ tmp,
    const int* __restrict__ poff, int* __restrict__ rowptr, float* __restrict__ dinv,
    int* __restrict__ col, int N, int NB, int E) {
  __shared__ int hist[128];
  __shared__ int sc[128];
  __shared__ int lcur[128];
  __shared__ unsigned buf[BCAP];
  int b = blockIdx.x;
  int n0 = b << BSH;
  int base = poff[(size_t)b * NBLK];
  int nxt = (b + 1 < NB) ? poff[(size_t)(b + 1) * NBLK] : E;
  int cnt = nxt - base;
  int tid = threadIdx.x;
  if (tid < 128) hist[tid] = 0;
  __syncthreads();
  for (int i = tid; i < cnt; i += 256) atomicAdd(&hist[(tmp[base + i] >> 20) & 127], 1);
  __syncthreads();
  // Hillis-Steele inclusive scan over 128 bins
  if (tid < 128) sc[tid] = hist[tid];
  __syncthreads();
  for (int ofs = 1; ofs < 128; ofs <<= 1) {
    int v = (tid < 128 && tid >= ofs) ? sc[tid - ofs] : 0;
    __syncthreads();
    if (tid < 128) sc[tid] += v;
    __syncthreads();
  }
  if (tid < 128) {
    int excl = sc[tid] - hist[tid];
    lcur[tid] = excl;
    int node = n0 + tid;
    if (node < N) {
      rowptr[node] = base + excl;
      dinv[node] = rsqrtf((float)hist[tid] + 1.0f);  // deg = in-degree + self loop
    }
  }
  if (b == 0 && tid == 0) rowptr[N] = E;
  __syncthreads();
  if (cnt <= BCAP) {
    for (int i = tid; i < cnt; i += 256) {
      unsigned pk = tmp[base + i];
      int p = atomicAdd(&lcur[(pk >> 20) & 127], 1);
      buf[p] = pk & 0xFFFFFu;
    }
    __syncthreads();
    for (int i = tid; i < cnt; i += 256) col[base + i] = (int)buf[i];
  } else {  // overflow fallback (statistically never for uniform dst)
    for (int i = tid; i < cnt; i += 256) {
      unsigned pk = tmp[base + i];
      int p = atomicAdd(&lcur[(pk >> 20) & 127], 1);
      col[base + p] = (int)(pk & 0xFFFFFu);
    }
  }
}

// ---------- MFMA GEMM: [M x 128] @ [128 x 128], bf16 MFMA, fp32 acc, bf16 out ----
#define WSTRIDE 136
template <int BF16IN>
__global__ __launch_bounds__(256) void k_gemm(const void* __restrict__ Ap,
    const float* __restrict__ W, bf16_t* __restrict__ Co, int M) {
  __shared__ bf16_t Wt[128 * WSTRIDE];
  int tid = threadIdx.x;
  for (int i = tid; i < 4096; i += 256) {
    int k = i >> 5;
    int nq = (i & 31) << 2;
    float4 w = *(const float4*)&W[k * CDIM + nq];
    Wt[(nq + 0) * WSTRIDE + k] = f2bf(w.x);
    Wt[(nq + 1) * WSTRIDE + k] = f2bf(w.y);
    Wt[(nq + 2) * WSTRIDE + k] = f2bf(w.z);
    Wt[(nq + 3) * WSTRIDE + k] = f2bf(w.w);
  }
  __syncthreads();

  int wave = tid >> 6;
  int lane = tid & 63;
  int m = lane & 15;
  int q = lane >> 4;
  int nstrips = (M + 63) >> 6;

  for (int s = blockIdx.x; s < nstrips; s += gridDim.x) {
    int rowA = s * 64 + wave * 16 + m;
    if (rowA > M - 1) rowA = M - 1;
    bf16x8 a[4];
#pragma unroll
    for (int c = 0; c < 4; c++) {
      if (BF16IN) {
        a[c] = *(const bf16x8*)((const bf16_t*)Ap + (size_t)rowA * CDIM + c * 32 + q * 8);
      } else {
        const float* ap = (const float*)Ap + (size_t)rowA * CDIM + c * 32 + q * 8;
        float4 f0 = *(const float4*)ap;
        float4 f1 = *(const float4*)(ap + 4);
        union { bf16x8 v; unsigned short u[8]; } ua;
        ua.u[0] = f2bf(f0.x); ua.u[1] = f2bf(f0.y); ua.u[2] = f2bf(f0.z); ua.u[3] = f2bf(f0.w);
        ua.u[4] = f2bf(f1.x); ua.u[5] = f2bf(f1.y); ua.u[6] = f2bf(f1.z); ua.u[7] = f2bf(f1.w);
        a[c] = ua.v;
      }
    }
#pragma unroll
    for (int t = 0; t < 8; t++) {
      f32x4 acc = {0.f, 0.f, 0.f, 0.f};
#pragma unroll
      for (int c = 0; c < 4; c++) {
        bf16x8 bv = *(const bf16x8*)&Wt[(t * 16 + m) * WSTRIDE + c * 32 + q * 8];
        acc = __builtin_amdgcn_mfma_f32_16x16x32_bf16(a[c], bv, acc, 0, 0, 0);
      }
#pragma unroll
      for (int r = 0; r < 4; r++) {
        int row = s * 64 + wave * 16 + q * 4 + r;
        if (row < M) Co[(size_t)row * CDIM + t * 16 + m] = f2bf(acc[r]);
      }
    }
  }
}

// ---------- per-node gather aggregation + bias + relu (one wave per node) ------
__global__ __launch_bounds__(256) void k_agg(const bf16_t* __restrict__ t,
    const int* __restrict__ rowptr, const int* __restrict__ col,
    const float* __restrict__ dinv, const float* __restrict__ bias,
    bf16_t* __restrict__ out, int N) {
  int wave = threadIdx.x >> 6;
  int lane = threadIdx.x & 63;
  int node = blockIdx.x * 4 + wave;
  if (node >= N) return;
  float di = dinv[node];
  unsigned su = ((const unsigned*)(t + (size_t)node * CDIM))[lane];
  float ax = bflo(su) * di;
  float ay = bfhi(su) * di;
  int beg = rowptr[node], end = rowptr[node + 1];
  for (int base = beg; base < end; base += 64) {
    int rem = end - base;
    int cnt = rem < 64 ? rem : 64;
    int sL = 0; float wL = 0.f;
    if (lane < cnt) { sL = col[base + lane]; wL = dinv[sL]; }
    int k = 0;
    for (; k + 3 < cnt; k += 4) {
      int s0 = __shfl(sL, k, 64),     s1 = __shfl(sL, k + 1, 64);
      int s2 = __shfl(sL, k + 2, 64), s3 = __shfl(sL, k + 3, 64);
      float w0 = __shfl(wL, k, 64),     w1 = __shfl(wL, k + 1, 64);
      float w2 = __shfl(wL, k + 2, 64), w3 = __shfl(wL, k + 3, 64);
      unsigned u0 = ((const unsigned*)(t + (size_t)s0 * CDIM))[lane];
      unsigned u1 = ((const unsigned*)(t + (size_t)s1 * CDIM))[lane];
      unsigned u2 = ((const unsigned*)(t + (size_t)s2 * CDIM))[lane];
      unsigned u3 = ((const unsigned*)(t + (size_t)s3 * CDIM))[lane];
      ax = fmaf(bflo(u0), w0, ax); ay = fmaf(bfhi(u0), w0, ay);
      ax = fmaf(bflo(u1), w1, ax); ay = fmaf(bfhi(u1), w1, ay);
      ax = fmaf(bflo(u2), w2, ax); ay = fmaf(bfhi(u2), w2, ay);
      ax = fmaf(bflo(u3), w3, ax); ay = fmaf(bfhi(u3), w3, ay);
    }
    for (; k < cnt; k++) {
      int s = __shfl(sL, k, 64);
      float w = __shfl(wL, k, 64);
      unsigned u = ((const unsigned*)(t + (size_t)s * CDIM))[lane];
      ax = fmaf(bflo(u), w, ax); ay = fmaf(bfhi(u), w, ay);
    }
  }
  float2 bb = ((const float2*)bias)[lane];
  float ox = fmaf(di, ax, bb.x);
  float oy = fmaf(di, ay, bb.y);
  ox = fmaxf(ox, 0.f); oy = fmaxf(oy, 0.f);
  unsigned o = ((unsigned)f2bf(oy) << 16) | f2bf(ox);
  ((unsigned*)(out + (size_t)node * CDIM))[lane] = o;
}

// ---------- global mean pool: node-parallel partial sums + atomics ----------
__global__ __launch_bounds__(256) void k_pool2(const bf16_t* __restrict__ h,
    const int* __restrict__ batch, float* __restrict__ gsum, int N) {
  int tid = threadIdx.x;
  int wave = tid >> 6, lane = tid & 63;
  int i0 = blockIdx.x * PCHUNK;
  int i1 = i0 + PCHUNK; if (i1 > N) i1 = N;
  float ax = 0.f, ay = 0.f;
  int curb = -1;
  for (int i = i0 + wave; i < i1; i += 4) {
    int b = batch[i];                 // wave-uniform broadcast load
    if (b != curb) {
      if (curb >= 0) {
        atomicAdd(&gsum[curb * CDIM + lane * 2], ax);
        atomicAdd(&gsum[curb * CDIM + lane * 2 + 1], ay);
      }
      curb = b; ax = 0.f; ay = 0.f;
    }
    unsigned u = ((const unsigned*)(h + (size_t)i * CDIM))[lane];
    ax += bflo(u); ay += bfhi(u);
  }
  if (curb >= 0) {
    atomicAdd(&gsum[curb * CDIM + lane * 2], ax);
    atomicAdd(&gsum[curb * CDIM + lane * 2 + 1], ay);
  }
}

// divide by per-graph node count (binary search over sorted batch), in place.
__global__ __launch_bounds__(128) void k_pooldiv(float* __restrict__ g,
    const int* __restrict__ batch, int N) {
  int b = blockIdx.x;
  int lo = 0, hi = N;
  while (lo < hi) { int mid = (lo + hi) >> 1; if (batch[mid] < b) lo = mid + 1; else hi = mid; }
  int s = lo;
  lo = 0; hi = N;
  int key = b + 1;
  while (lo < hi) { int mid = (lo + hi) >> 1; if (batch[mid] < key) lo = mid + 1; else hi = mid; }
  float inv = 1.f / fmaxf((float)(lo - s), 1.f);
  g[b * CDIM + threadIdx.x] *= inv;
}

// ---------- MLP head ----------
__global__ __launch_bounds__(512) void k_mlp1(const float* __restrict__ g,
    const float* __restrict__ W, const float* __restrict__ b, float* __restrict__ o) {
  __shared__ float gs[CDIM];
  int bi = blockIdx.x, tid = threadIdx.x;
  if (tid < CDIM) gs[tid] = g[bi * CDIM + tid];
  __syncthreads();
  if (tid < 500) {
    float acc = b[tid];
#pragma unroll 4
    for (int k = 0; k < CDIM; k++) acc = fmaf(gs[k], W[k * 500 + tid], acc);
    o[bi * 500 + tid] = fmaxf(acc, 0.f);
  }
}

__global__ __launch_bounds__(128) void k_mlp2(const float* __restrict__ a,
    const float* __restrict__ W, const float* __restrict__ b, float* __restrict__ o) {
  __shared__ float as[500];
  int bi = blockIdx.x, tid = threadIdx.x;
  for (int k = tid; k < 500; k += 128) as[k] = a[bi * 500 + k];
  __syncthreads();
  if (tid < 100) {
    float acc = b[tid];
    for (int k = 0; k < 500; k++) acc = fmaf(as[k], W[k * 100 + tid], acc);
    o[bi * 100 + tid] = fmaxf(acc, 0.f);
  }
}

__global__ __launch_bounds__(64) void k_mlp3(const float* __restrict__ a,
    const float* __restrict__ w, const float* __restrict__ b, float* __restrict__ o) {
  int bi = blockIdx.x, lane = threadIdx.x;
  float v = a[bi * 100 + lane] * w[lane];
  if (lane + 64 < 100) v = fmaf(a[bi * 100 + lane + 64], w[lane + 64], v);
#pragma unroll
  for (int ofs = 32; ofs > 0; ofs >>= 1) v += __shfl_down(v, ofs, 64);
  if (lane == 0) o[bi] = v + b[0];
}

static inline size_t align_up(size_t v) { return (v + 255) & ~(size_t)255; }

extern "C" void kernel_launch(void* const* d_in, const int* in_sizes, int n_in,
                              void* d_out, int out_size, void* d_ws, size_t ws_size,
                              hipStream_t stream) {
  const float* x   = (const float*)d_in[0];
  const int*   ei  = (const int*)d_in[1];
  const int*   bat = (const int*)d_in[2];
  const float* W1  = (const float*)d_in[3];
  const float* b1  = (const float*)d_in[4];
  const float* W2  = (const float*)d_in[5];
  const float* b2  = (const float*)d_in[6];
  const float* Wm1 = (const float*)d_in[7];
  const float* bm1 = (const float*)d_in[8];
  const float* Wm2 = (const float*)d_in[9];
  const float* bm2 = (const float*)d_in[10];
  const float* Wm3 = (const float*)d_in[11];
  const float* bm3 = (const float*)d_in[12];
  float* out = (float*)d_out;

  const int E = in_sizes[1] / 2;
  const int N = in_sizes[2];
  const int* src = ei;
  const int* dst = ei + E;
  const int NB = (N + 127) >> BSH;
  const int M  = NB * NBLK;              // phist elements
  const int G2 = (M + 4095) / 4096;

  char* p = (char*)d_ws;
  bf16_t* t    = (bf16_t*)p;   p += align_up((size_t)N * CDIM * 2);
  bf16_t* h    = (bf16_t*)p;   p += align_up((size_t)N * CDIM * 2);
  int* rowptr  = (int*)p;      p += align_up((size_t)(N + 1) * 4);
  int* colx    = (int*)p;      p += align_up((size_t)E * 4);
  unsigned* tmp= (unsigned*)p; p += align_up((size_t)E * 4);
  float* dinv  = (float*)p;    p += align_up((size_t)N * 4);
  int* phist   = (int*)p;      p += align_up((size_t)M * 4);
  int* poff    = (int*)p;      p += align_up((size_t)M * 4);
  int* bsumsB  = (int*)p;      p += align_up((size_t)G2 * 4);
  int* boffsB  = (int*)p;      p += align_up((size_t)(G2 + 1) * 4);
  float* gb    = (float*)p;    p += align_up((size_t)NGRAPH * CDIM * 4);
  float* m1    = (float*)p;    p += align_up((size_t)NGRAPH * 500 * 4);
  float* m2    = (float*)p;    p += align_up((size_t)NGRAPH * 100 * 4);
  (void)ws_size; (void)n_in; (void)out_size;

  hipMemsetAsync(gb, 0, (size_t)NGRAPH * CDIM * 4, stream);

  k_phist<<<NBLK, 1024, 0, stream>>>(dst, phist, E, NB);
  k_bsum<<<G2, 1024, 0, stream>>>(phist, bsumsB, M);
  k_boff<<<1, 1024, 0, stream>>>(bsumsB, boffsB, G2);
  k_scan3<<<G2, 1024, 0, stream>>>(phist, boffsB, poff, M);
  k_pscatter<<<NBLK, 1024, 0, stream>>>(src, dst, poff, tmp, E, NB);
  k_csort2<<<NB, 256, 0, stream>>>(tmp, poff, rowptr, dinv, colx, N, NB, E);

  int nstrips = (N + 63) >> 6;
  int gblocks = nstrips < 1024 ? nstrips : 1024;
  k_gemm<0><<<gblocks, 256, 0, stream>>>(x, W1, t, N);
  k_agg<<<(N + 3) / 4, 256, 0, stream>>>(t, rowptr, colx, dinv, b1, h, N);
  k_gemm<1><<<gblocks, 256, 0, stream>>>(h, W2, t, N);
  k_agg<<<(N + 3) / 4, 256, 0, stream>>>(t, rowptr, colx, dinv, b2, h, N);

  k_pool2<<<(N + PCHUNK - 1) / PCHUNK, 256, 0, stream>>>(h, bat, gb, N);
  k_pooldiv<<<NGRAPH, 128, 0, stream>>>(gb, bat, N);
  k_mlp1<<<NGRAPH, 512, 0, stream>>>(gb, Wm1, bm1, m1);
  k_mlp2<<<NGRAPH, 128, 0, stream>>>(m1, Wm2, bm2, m2);
  k_mlp3<<<NGRAPH, 64, 0, stream>>>(m2, Wm3, bm3, out);
}